// Round 2
// baseline (288.935 us; speedup 1.0000x reference)
//
#include <hip/hip_runtime.h>
#include <hip/hip_bf16.h>

// SegmentLinear: y = sum_c (sx_c*sw_c) * (qx_c @ qw_c^T), int8-exact path.
// N = K = O = 4096, CHUNKS = 4, cs = 1024.

constexpr int NDIM = 4096;
constexpr int TOTAL4 = (NDIM * NDIM) / 4;   // float4 count per matrix

typedef int i32x4 __attribute__((ext_vector_type(4)));

// ---------------------------------------------------------------- amax pass
__global__ __launch_bounds__(256) void amax_kernel(
    const float* __restrict__ x, const float* __restrict__ w,
    unsigned int* __restrict__ amax) {
  const int t = threadIdx.x;
  const int c = blockIdx.x & 3;  // grid stride (1024*256 float4) is a multiple
                                 // of K/4=1024 -> whole block stays in chunk c
  float mx = 0.f, mw = 0.f;
  const float4* x4 = (const float4*)x;
  const float4* w4 = (const float4*)w;
  const int stride = 1024 * 256;
  for (int i = blockIdx.x * 256 + t; i < TOTAL4; i += stride) {
    float4 v = x4[i];
    mx = fmaxf(mx, fmaxf(fmaxf(fabsf(v.x), fabsf(v.y)),
                         fmaxf(fabsf(v.z), fabsf(v.w))));
    float4 u = w4[i];
    mw = fmaxf(mw, fmaxf(fmaxf(fabsf(u.x), fabsf(u.y)),
                         fmaxf(fabsf(u.z), fabsf(u.w))));
  }
  __shared__ float r0[256], r1[256];
  r0[t] = mx; r1[t] = mw;
  __syncthreads();
  for (int off = 128; off; off >>= 1) {
    if (t < off) {
      r0[t] = fmaxf(r0[t], r0[t + off]);
      r1[t] = fmaxf(r1[t], r1[t + off]);
    }
    __syncthreads();
  }
  if (t == 0) {
    atomicMax(&amax[c],     __float_as_uint(r0[0]));  // non-neg: uint order == float order
    atomicMax(&amax[4 + c], __float_as_uint(r1[0]));
  }
}

// ------------------------------------------------------------- quantize pass
__device__ __forceinline__ signed char quant1(float v, float s) {
  float r = rintf(v / s);                       // round-half-even, IEEE div: matches numpy
  r = fminf(fmaxf(r, -127.f), 127.f);
  return (signed char)(int)r;
}

__global__ __launch_bounds__(256) void quant_kernel(
    const float* __restrict__ x, const float* __restrict__ w,
    const unsigned int* __restrict__ amax,
    signed char* __restrict__ qx, signed char* __restrict__ qw) {
  const int t = threadIdx.x;
  const int c = blockIdx.x & 3;
  const float sx = fmaxf(__uint_as_float(amax[c])     / 127.0f, 1e-8f);
  const float sw = fmaxf(__uint_as_float(amax[4 + c]) / 127.0f, 1e-8f);
  const float4* x4 = (const float4*)x;
  const float4* w4 = (const float4*)w;
  char4* qx4 = (char4*)qx;
  char4* qw4 = (char4*)qw;
  const int stride = 1024 * 256;
  for (int i = blockIdx.x * 256 + t; i < TOTAL4; i += stride) {
    float4 v = x4[i];
    char4 q;
    q.x = quant1(v.x, sx); q.y = quant1(v.y, sx);
    q.z = quant1(v.z, sx); q.w = quant1(v.w, sx);
    qx4[i] = q;
    float4 u = w4[i];
    char4 p;
    p.x = quant1(u.x, sw); p.y = quant1(u.y, sw);
    p.z = quant1(u.z, sw); p.w = quant1(u.w, sw);
    qw4[i] = p;
  }
}

// ------------------------------------------------------------------ i8 GEMM
__device__ __forceinline__ void async16(const void* g, void* l) {
  __builtin_amdgcn_global_load_lds(
      (const __attribute__((address_space(1))) void*)g,
      (__attribute__((address_space(3))) void*)l, 16, 0, 0);
}

// 128x128 tile, BK=64 int8 bytes, double-buffered LDS, 4 waves (2x2),
// 64x64 out/wave. mfma_i32_16x16x64_i8: lane = r + 16*kg holds 16 k-bytes.
// Swizzle: LDS[row][slot] holds global[row][slot ^ ((row>>1)&3)] (16B slots).
//   -> every 8-lane ds_read_b128 group hits 8 distinct 16B bank positions.
// Pipeline: stage tile t+1 before computing tile t; one __syncthreads per
// K-step (its implicit vmcnt(0)+lgkmcnt(0) drain provides all ordering).
__global__ __launch_bounds__(256, 2) void gemm_i8_kernel(
    const signed char* __restrict__ qx, const signed char* __restrict__ qw,
    const unsigned int* __restrict__ amax, float* __restrict__ out) {
  __shared__ __align__(128) signed char lds_a[2][8192];
  __shared__ __align__(128) signed char lds_b[2][8192];

  const int t = threadIdx.x;
  const int lane = t & 63;
  const int wave = t >> 6;

  // bijective XCD swizzle (1024 blocks % 8 == 0): each XCD owns 128
  // consecutive tiles = 4 full by-rows -> A-panel L2-resident per XCD.
  const int id = blockIdx.x;
  const int sid = (id & 7) * 128 + (id >> 3);
  const int brow = (sid >> 5) * 128;
  const int bcol = (sid & 31) * 128;

  const int wr = wave >> 1;
  const int wc = wave & 1;

  // per-chunk combined scales (exactly as reference computes them)
  float s0, s1, s2, s3;
  {
    float sx0 = fmaxf(__uint_as_float(amax[0]) / 127.0f, 1e-8f);
    float sx1 = fmaxf(__uint_as_float(amax[1]) / 127.0f, 1e-8f);
    float sx2 = fmaxf(__uint_as_float(amax[2]) / 127.0f, 1e-8f);
    float sx3 = fmaxf(__uint_as_float(amax[3]) / 127.0f, 1e-8f);
    float sw0 = fmaxf(__uint_as_float(amax[4]) / 127.0f, 1e-8f);
    float sw1 = fmaxf(__uint_as_float(amax[5]) / 127.0f, 1e-8f);
    float sw2 = fmaxf(__uint_as_float(amax[6]) / 127.0f, 1e-8f);
    float sw3 = fmaxf(__uint_as_float(amax[7]) / 127.0f, 1e-8f);
    s0 = sx0 * sw0; s1 = sx1 * sw1; s2 = sx2 * sw2; s3 = sx3 * sw3;
  }

  // staging: issue i of wave w, lane l writes LDS bytes [w*1024 + l*16] (+4096)
  //   -> LDS row ar = w*16 + (l>>2) (+64), slot sl = l&3 (linear dest).
  // Global source pre-swizzled with the same involution as the read side.
  const int ar0 = wave * 16 + (lane >> 2);
  const int ar1 = ar0 + 64;
  const int sl = lane & 3;
  const signed char* gax0 = qx + (size_t)(brow + ar0) * NDIM + ((sl ^ ((ar0 >> 1) & 3)) << 4);
  const signed char* gax1 = qx + (size_t)(brow + ar1) * NDIM + ((sl ^ ((ar1 >> 1) & 3)) << 4);
  const signed char* gbx0 = qw + (size_t)(bcol + ar0) * NDIM + ((sl ^ ((ar0 >> 1) & 3)) << 4);
  const signed char* gbx1 = qw + (size_t)(bcol + ar1) * NDIM + ((sl ^ ((ar1 >> 1) & 3)) << 4);
  const int ldsoff = wave * 1024;

  // fragment reads: row = wtile + m*16 + (lane&15), k-slot kg = lane>>4
  const int ra = wr * 64 + (lane & 15);
  const int rb = wc * 64 + (lane & 15);
  const int kg = lane >> 4;
  const int offa = ra * 64 + ((kg ^ ((ra >> 1) & 3)) << 4);
  const int offb = rb * 64 + ((kg ^ ((rb >> 1) & 3)) << 4);

  i32x4 iacc[4][4];
  float facc[4][4][4];
#pragma unroll
  for (int m = 0; m < 4; ++m)
#pragma unroll
    for (int n = 0; n < 4; ++n) {
      iacc[m][n] = i32x4{0, 0, 0, 0};
#pragma unroll
      for (int j = 0; j < 4; ++j) facc[m][n][j] = 0.f;
    }

#define STAGE(BUF, T)                                        \
  do {                                                       \
    const int kt_ = (T) * 64;                                \
    async16(gax0 + kt_, &lds_a[BUF][ldsoff]);                \
    async16(gax1 + kt_, &lds_a[BUF][ldsoff + 4096]);         \
    async16(gbx0 + kt_, &lds_b[BUF][ldsoff]);                \
    async16(gbx1 + kt_, &lds_b[BUF][ldsoff + 4096]);         \
  } while (0)

#define COMPUTE(BUF)                                                    \
  do {                                                                  \
    i32x4 av[4], bv[4];                                                 \
    _Pragma("unroll")                                                   \
    for (int m = 0; m < 4; ++m)                                         \
      av[m] = *(const i32x4*)&lds_a[BUF][offa + m * 1024];              \
    _Pragma("unroll")                                                   \
    for (int n = 0; n < 4; ++n)                                         \
      bv[n] = *(const i32x4*)&lds_b[BUF][offb + n * 1024];              \
    _Pragma("unroll")                                                   \
    for (int m = 0; m < 4; ++m)                                         \
      _Pragma("unroll")                                                 \
      for (int n = 0; n < 4; ++n)                                       \
        iacc[m][n] = __builtin_amdgcn_mfma_i32_16x16x64_i8(             \
            av[m], bv[n], iacc[m][n], 0, 0, 0);                         \
  } while (0)

#define FOLD(S)                                                         \
  do {                                                                  \
    _Pragma("unroll")                                                   \
    for (int m = 0; m < 4; ++m)                                         \
      _Pragma("unroll")                                                 \
      for (int n = 0; n < 4; ++n) {                                     \
        _Pragma("unroll")                                               \
        for (int j = 0; j < 4; ++j) facc[m][n][j] += (S) * (float)iacc[m][n][j]; \
        iacc[m][n] = i32x4{0, 0, 0, 0};                                 \
      }                                                                 \
  } while (0)

  STAGE(0, 0);
#pragma unroll 1
  for (int tp = 0; tp < 32; ++tp) {
    const int t1 = 2 * tp + 1;
    __syncthreads();        // drains vmcnt(0): tile 2tp ready; prev reads done
    STAGE(1, t1);           // prefetch odd tile while computing even
    COMPUTE(0);
    __syncthreads();        // tile t1 ready; all waves done reading buf0
    if (t1 < 63) STAGE(0, t1 + 1);
    COMPUTE(1);
    if (t1 == 15) FOLD(s0);
    else if (t1 == 31) FOLD(s1);
    else if (t1 == 47) FOLD(s2);
  }
  FOLD(s3);

  // C/D layout (16x16): col = lane&15, row = (lane>>4)*4 + j
  const int orow = brow + wr * 64 + (lane >> 4) * 4;
  const int ocol = bcol + wc * 64 + (lane & 15);
#pragma unroll
  for (int m = 0; m < 4; ++m)
#pragma unroll
    for (int n = 0; n < 4; ++n)
#pragma unroll
      for (int j = 0; j < 4; ++j)
        out[(size_t)(orow + m * 16 + j) * NDIM + (ocol + n * 16)] = facc[m][n][j];
#undef STAGE
#undef COMPUTE
#undef FOLD
}

// ---------------------------------------------------------------- launcher
extern "C" void kernel_launch(void* const* d_in, const int* in_sizes, int n_in,
                              void* d_out, int out_size, void* d_ws, size_t ws_size,
                              hipStream_t stream) {
  const float* x = (const float*)d_in[0];
  const float* w = (const float*)d_in[1];
  float* out = (float*)d_out;

  unsigned int* amax = (unsigned int*)d_ws;                 // 8 uints
  signed char* qx = (signed char*)d_ws + 256;               // 16 MiB
  signed char* qw = qx + (size_t)NDIM * NDIM;               // 16 MiB

  hipMemsetAsync(d_ws, 0, 256, stream);
  amax_kernel<<<1024, 256, 0, stream>>>(x, w, amax);
  quant_kernel<<<1024, 256, 0, stream>>>(x, w, amax, qx, qw);
  gemm_i8_kernel<<<1024, 256, 0, stream>>>(qx, qw, amax, out);
}

// Round 3
// 155.731 us; speedup vs baseline: 1.8553x; 1.8553x over previous
//
#include <hip/hip_runtime.h>
#include <hip/hip_bf16.h>

// SegmentLinear: y = sum_c (sx_c*sw_c) * (qx_c @ qw_c^T), int8-exact path.
// N = K = O = 4096, CHUNKS = 4, cs = 1024.

constexpr int NDIM = 4096;
constexpr int TOTAL4 = (NDIM * NDIM) / 4;   // float4 count per matrix

typedef int i32x4 __attribute__((ext_vector_type(4)));

// ---------------------------------------------------------------- amax pass
__global__ __launch_bounds__(256) void amax_kernel(
    const float* __restrict__ x, const float* __restrict__ w,
    unsigned int* __restrict__ amax) {
  const int t = threadIdx.x;
  const int c = blockIdx.x & 3;  // grid stride (1024*256 float4) is a multiple
                                 // of K/4=1024 -> whole block stays in chunk c
  float mx = 0.f, mw = 0.f;
  const float4* x4 = (const float4*)x;
  const float4* w4 = (const float4*)w;
  const int stride = 1024 * 256;
  for (int i = blockIdx.x * 256 + t; i < TOTAL4; i += stride) {
    float4 v = x4[i];
    mx = fmaxf(mx, fmaxf(fmaxf(fabsf(v.x), fabsf(v.y)),
                         fmaxf(fabsf(v.z), fabsf(v.w))));
    float4 u = w4[i];
    mw = fmaxf(mw, fmaxf(fmaxf(fabsf(u.x), fabsf(u.y)),
                         fmaxf(fabsf(u.z), fabsf(u.w))));
  }
  __shared__ float r0[256], r1[256];
  r0[t] = mx; r1[t] = mw;
  __syncthreads();
  for (int off = 128; off; off >>= 1) {
    if (t < off) {
      r0[t] = fmaxf(r0[t], r0[t + off]);
      r1[t] = fmaxf(r1[t], r1[t + off]);
    }
    __syncthreads();
  }
  if (t == 0) {
    atomicMax(&amax[c],     __float_as_uint(r0[0]));  // non-neg: uint order == float order
    atomicMax(&amax[4 + c], __float_as_uint(r1[0]));
  }
}

// ------------------------------------------------------------- quantize pass
__device__ __forceinline__ signed char quant1(float v, float s) {
  float r = rintf(v / s);                       // round-half-even, IEEE div: matches numpy
  r = fminf(fmaxf(r, -127.f), 127.f);
  return (signed char)(int)r;
}

__global__ __launch_bounds__(256) void quant_kernel(
    const float* __restrict__ x, const float* __restrict__ w,
    const unsigned int* __restrict__ amax,
    signed char* __restrict__ qx, signed char* __restrict__ qw) {
  const int t = threadIdx.x;
  const int c = blockIdx.x & 3;
  const float sx = fmaxf(__uint_as_float(amax[c])     / 127.0f, 1e-8f);
  const float sw = fmaxf(__uint_as_float(amax[4 + c]) / 127.0f, 1e-8f);
  const float4* x4 = (const float4*)x;
  const float4* w4 = (const float4*)w;
  char4* qx4 = (char4*)qx;
  char4* qw4 = (char4*)qw;
  const int stride = 1024 * 256;
  for (int i = blockIdx.x * 256 + t; i < TOTAL4; i += stride) {
    float4 v = x4[i];
    char4 q;
    q.x = quant1(v.x, sx); q.y = quant1(v.y, sx);
    q.z = quant1(v.z, sx); q.w = quant1(v.w, sx);
    qx4[i] = q;
    float4 u = w4[i];
    char4 p;
    p.x = quant1(u.x, sw); p.y = quant1(u.y, sw);
    p.z = quant1(u.z, sw); p.w = quant1(u.w, sw);
    qw4[i] = p;
  }
}

// ------------------------------------------------------------------ i8 GEMM
__device__ __forceinline__ void async16(const void* g, void* l) {
  __builtin_amdgcn_global_load_lds(
      (const __attribute__((address_space(1))) void*)g,
      (__attribute__((address_space(3))) void*)l, 16, 0, 0);
}

// 128x128 tile, BK=64 int8 bytes. 4 waves (2x2), 64x64 out/wave.
// 4-buffer, depth-3 pipeline with COUNTED vmcnt (never drains to 0 in the
// steady loop) + raw s_barrier. Per K-step:
//   vmcnt(8)  -> my stage-t loads retired (stages t+1,t+2 = 8 stay in flight)
//   s_barrier -> all waves' stage-t data visible in LDS
//   COMPUTE   -> 8 ds_read_b128 + 16 mfma_i32_16x16x64_i8 (setprio 1)
//   lgkmcnt(0)-> my reads of buf done
//   s_barrier -> everyone's reads done => safe to re-stage this buf at t+3
// Swizzle (conflict-free, verified R2): LDS[row][slot] = glob[row][slot ^ ((row>>1)&3)],
// same involution on pre-swizzled global source (linear gload_lds dest) + read addr.
__global__ __launch_bounds__(256, 2) void gemm_i8_kernel(
    const signed char* __restrict__ qx, const signed char* __restrict__ qw,
    const unsigned int* __restrict__ amax, float* __restrict__ out) {
  __shared__ __align__(1024) signed char lds_a[4][8192];
  __shared__ __align__(1024) signed char lds_b[4][8192];

  const int t = threadIdx.x;
  const int lane = t & 63;
  const int wave = t >> 6;
  const int brow = blockIdx.y * 128;   // plain 2D raster (R1-proven L2 locality)
  const int bcol = blockIdx.x * 128;
  const int wr = wave >> 1;
  const int wc = wave & 1;

  // staging addresses: issue i of wave w, lane l -> LDS row ar, 16B slot sl
  const int ar0 = wave * 16 + (lane >> 2);
  const int ar1 = ar0 + 64;
  const int sl = lane & 3;
  const signed char* gax0 = qx + (size_t)(brow + ar0) * NDIM + ((sl ^ ((ar0 >> 1) & 3)) << 4);
  const signed char* gax1 = qx + (size_t)(brow + ar1) * NDIM + ((sl ^ ((ar1 >> 1) & 3)) << 4);
  const signed char* gbx0 = qw + (size_t)(bcol + ar0) * NDIM + ((sl ^ ((ar0 >> 1) & 3)) << 4);
  const signed char* gbx1 = qw + (size_t)(bcol + ar1) * NDIM + ((sl ^ ((ar1 >> 1) & 3)) << 4);
  const int ldsoff = wave * 1024;

  // fragment reads: row = wtile + m*16 + (lane&15), k-slot kg = lane>>4
  const int ra = wr * 64 + (lane & 15);
  const int rb = wc * 64 + (lane & 15);
  const int kg = lane >> 4;
  const int offa = ra * 64 + ((kg ^ ((ra >> 1) & 3)) << 4);
  const int offb = rb * 64 + ((kg ^ ((rb >> 1) & 3)) << 4);

#define STAGE(BUF, T)                                        \
  do {                                                       \
    const int kt_ = (T) * 64;                                \
    async16(gax0 + kt_, &lds_a[BUF][ldsoff]);                \
    async16(gax1 + kt_, &lds_a[BUF][ldsoff + 4096]);         \
    async16(gbx0 + kt_, &lds_b[BUF][ldsoff]);                \
    async16(gbx1 + kt_, &lds_b[BUF][ldsoff + 4096]);         \
  } while (0)

  // prologue: 3 stages in flight (12 loads)
  STAGE(0, 0);
  STAGE(1, 1);
  STAGE(2, 2);

  // per-chunk combined scales (exactly as reference computes them)
  const float s0 = fmaxf(__uint_as_float(amax[0]) / 127.0f, 1e-8f) *
                   fmaxf(__uint_as_float(amax[4]) / 127.0f, 1e-8f);
  const float s1 = fmaxf(__uint_as_float(amax[1]) / 127.0f, 1e-8f) *
                   fmaxf(__uint_as_float(amax[5]) / 127.0f, 1e-8f);
  const float s2 = fmaxf(__uint_as_float(amax[2]) / 127.0f, 1e-8f) *
                   fmaxf(__uint_as_float(amax[6]) / 127.0f, 1e-8f);
  const float s3 = fmaxf(__uint_as_float(amax[3]) / 127.0f, 1e-8f) *
                   fmaxf(__uint_as_float(amax[7]) / 127.0f, 1e-8f);

  i32x4 iacc[4][4];
  float facc[4][4][4];
#pragma unroll
  for (int m = 0; m < 4; ++m)
#pragma unroll
    for (int n = 0; n < 4; ++n) {
      iacc[m][n] = i32x4{0, 0, 0, 0};
#pragma unroll
      for (int j = 0; j < 4; ++j) facc[m][n][j] = 0.f;
    }

#define COMPUTE(BUF)                                                    \
  do {                                                                  \
    i32x4 av[4], bv[4];                                                 \
    _Pragma("unroll")                                                   \
    for (int m = 0; m < 4; ++m)                                         \
      av[m] = *(const i32x4*)&lds_a[BUF][offa + m * 1024];              \
    _Pragma("unroll")                                                   \
    for (int n = 0; n < 4; ++n)                                         \
      bv[n] = *(const i32x4*)&lds_b[BUF][offb + n * 1024];              \
    __builtin_amdgcn_s_setprio(1);                                      \
    _Pragma("unroll")                                                   \
    for (int m = 0; m < 4; ++m)                                         \
      _Pragma("unroll")                                                 \
      for (int n = 0; n < 4; ++n)                                       \
        iacc[m][n] = __builtin_amdgcn_mfma_i32_16x16x64_i8(             \
            av[m], bv[n], iacc[m][n], 0, 0, 0);                         \
    __builtin_amdgcn_s_setprio(0);                                      \
  } while (0)

#define FOLD(S)                                                         \
  do {                                                                  \
    _Pragma("unroll")                                                   \
    for (int m = 0; m < 4; ++m)                                         \
      _Pragma("unroll")                                                 \
      for (int n = 0; n < 4; ++n) {                                     \
        _Pragma("unroll")                                               \
        for (int j = 0; j < 4; ++j) facc[m][n][j] += (S) * (float)iacc[m][n][j]; \
        iacc[m][n] = i32x4{0, 0, 0, 0};                                 \
      }                                                                 \
  } while (0)

#define BODY(B)                                                          \
  do {                                                                   \
    const int t_ = t4 * 4 + (B);                                         \
    asm volatile("s_waitcnt vmcnt(8)" ::: "memory");                     \
    __builtin_amdgcn_sched_barrier(0);                                   \
    __builtin_amdgcn_s_barrier();                                        \
    __builtin_amdgcn_sched_barrier(0);                                   \
    COMPUTE(B);                                                          \
    asm volatile("s_waitcnt lgkmcnt(0)" ::: "memory");                   \
    __builtin_amdgcn_sched_barrier(0);                                   \
    __builtin_amdgcn_s_barrier();                                        \
    __builtin_amdgcn_sched_barrier(0);                                   \
    if ((B) == 0 || t4 < 15) STAGE(((B) + 3) & 3, t_ + 3);               \
    if (((B) & 3) == 3 && (t4 & 3) == 3) {                               \
      const int ci = t4 >> 2;                                            \
      const float sc_ = ci == 0 ? s0 : ci == 1 ? s1 : ci == 2 ? s2 : s3; \
      FOLD(sc_);                                                         \
    }                                                                    \
  } while (0)

#pragma unroll 1
  for (int t4 = 0; t4 < 16; ++t4) {
    BODY(0);
    BODY(1);
    BODY(2);
    BODY(3);
  }

  // C/D layout (16x16): col = lane&15, row = (lane>>4)*4 + j
  const int orow = brow + wr * 64 + (lane >> 4) * 4;
  const int ocol = bcol + wc * 64 + (lane & 15);
#pragma unroll
  for (int m = 0; m < 4; ++m)
#pragma unroll
    for (int n = 0; n < 4; ++n)
#pragma unroll
      for (int j = 0; j < 4; ++j)
        out[(size_t)(orow + m * 16 + j) * NDIM + (ocol + n * 16)] = facc[m][n][j];
#undef STAGE
#undef COMPUTE
#undef FOLD
#undef BODY
}

// ---------------------------------------------------------------- launcher
extern "C" void kernel_launch(void* const* d_in, const int* in_sizes, int n_in,
                              void* d_out, int out_size, void* d_ws, size_t ws_size,
                              hipStream_t stream) {
  const float* x = (const float*)d_in[0];
  const float* w = (const float*)d_in[1];
  float* out = (float*)d_out;

  unsigned int* amax = (unsigned int*)d_ws;                 // 8 uints
  signed char* qx = (signed char*)d_ws + 256;               // 16 MiB
  signed char* qw = qx + (size_t)NDIM * NDIM;               // 16 MiB

  hipMemsetAsync(d_ws, 0, 256, stream);
  amax_kernel<<<1024, 256, 0, stream>>>(x, w, amax);
  quant_kernel<<<1024, 256, 0, stream>>>(x, w, amax, qx, qw);
  dim3 grid(NDIM / 128, NDIM / 128);
  gemm_i8_kernel<<<grid, 256, 0, stream>>>(qx, qw, amax, out);
}